// Round 1
// baseline (221.149 us; speedup 1.0000x reference)
//
#include <hip/hip_runtime.h>
#include <hip/hip_bf16.h>

#define BTC 16
#define NC 1024
#define DC 128
#define HC 8
#define HDC 16

typedef __attribute__((ext_vector_type(8))) short bf16x8;   // 8 bf16 = 4 VGPR
typedef __attribute__((ext_vector_type(4))) float f32x4;    // MFMA C/D frag 16x16
typedef __attribute__((ext_vector_type(16))) float f32x16;  // MFMA C/D frag 32x32
typedef __attribute__((ext_vector_type(4))) short short4v;  // 8B pack

#if __has_builtin(__builtin_amdgcn_exp2f)
#define EXP2F(x) __builtin_amdgcn_exp2f(x)
#else
#define EXP2F(x) exp2f(x)
#endif

// q scale: 0.25 (1/sqrt(HD)) * log2(e)  -> attention uses exp2 directly
#define QSCALE 0.36067376022224085f

union PK2 { short4v s4; __hip_bfloat162 h2[2]; };
union PK8 { bf16x8 v; short s[8]; __hip_bfloat162 h2[4]; };

static __device__ inline short f2bf(float f) {               // RNE f32->bf16
    unsigned u = __builtin_bit_cast(unsigned, f);
    u += 0x7fffu + ((u >> 16) & 1u);
    return (short)(u >> 16);
}

// ---------------- prep: fp32 -> bf16 for x and the 4 weight matrices --------
__global__ __launch_bounds__(256)
void prep_kernel(const float* __restrict__ x,
                 const float* __restrict__ Wq, const float* __restrict__ Wk,
                 const float* __restrict__ Wv, const float* __restrict__ Wo,
                 short* __restrict__ xbf, short* __restrict__ Wbf)
{
    int gid  = blockIdx.x * 256 + threadIdx.x;
    int base = gid * 4;
    const float* src;
    short* dst;
    if (base < 2097152) {                      // x: 16*1024*128
        src = x + base; dst = xbf + base;
    } else {
        int idx = base - 2097152;              // 0..65535 over 4 W's
        int w   = idx >> 14;
        int off = idx & 16383;
        src = ((w == 0) ? Wq : (w == 1) ? Wk : (w == 2) ? Wv : Wo) + off;
        dst = Wbf + w * 16384 + off;
    }
    float4 v = *(const float4*)src;
    PK2 pk;
    pk.h2[0] = __float22bfloat162_rn(make_float2(v.x, v.y));
    pk.h2[1] = __float22bfloat162_rn(make_float2(v.z, v.w));
    *(short4v*)dst = pk.s4;
}

// ---------------- MFMA projection, C = X @ W^T + b --------------------------
// block = 256 thr (4 waves), wave = 16 rows x 128 cols, K-loop 4x32.
// y = 0: q (scale QSCALE), 1: k, 2: v stored transposed vt[bt][d][n] via an
// LDS transpose tile -> coalesced 16B stores (replaces 2-B scattered stores).
__global__ __launch_bounds__(256)
void proj_qkv(const short* __restrict__ xbf, const short* __restrict__ Wbf,
              const float* __restrict__ bq, const float* __restrict__ bk,
              const float* __restrict__ bv,
              short* __restrict__ qo, short* __restrict__ ko, short* __restrict__ vto)
{
    __shared__ short T[128 * 72];        // 18.4 KB transpose tile (y==2 only)

    const int y = blockIdx.y;
    const short* W = Wbf + y * 16384;
    const float* bias = (y == 0) ? bq : (y == 1) ? bk : bv;
    const float scale = (y == 0) ? QSCALE : 1.0f;

    const int tid  = threadIdx.x;
    const int wave = tid >> 6;
    const int lane = tid & 63;
    const int l15  = lane & 15;
    const int quad = lane >> 4;
    const int rowA = blockIdx.x * 64 + wave * 16;

    f32x4 acc[8];
#pragma unroll
    for (int t = 0; t < 8; ++t) acc[t] = (f32x4){0.f, 0.f, 0.f, 0.f};

#pragma unroll
    for (int kk = 0; kk < DC; kk += 32) {
        bf16x8 Af = *(const bf16x8*)&xbf[(size_t)(rowA + l15) * DC + kk + quad * 8];
#pragma unroll
        for (int t = 0; t < 8; ++t) {
            bf16x8 Bf = *(const bf16x8*)&W[(t * 16 + l15) * DC + kk + quad * 8];
            acc[t] = __builtin_amdgcn_mfma_f32_16x16x32_bf16(Af, Bf, acc[t], 0, 0, 0);
        }
    }

    if (y == 2) {
        // transpose through LDS: T[c][local_row], row stride 72 shorts (144 B,
        // 16-B aligned for b128 reads; bank-minimal b64 writes)
#pragma unroll
        for (int t = 0; t < 8; ++t) {
            int c = t * 16 + l15;
            float b = bias[c];
            PK2 pk;
            pk.h2[0] = __float22bfloat162_rn(make_float2(acc[t][0] + b, acc[t][1] + b));
            pk.h2[1] = __float22bfloat162_rn(make_float2(acc[t][2] + b, acc[t][3] + b));
            *(short4v*)&T[c * 72 + wave * 16 + quad * 4] = pk.s4;
        }
        __syncthreads();                  // y uniform per block: no divergence
        const int bt = blockIdx.x >> 4;
        const int n0 = (blockIdx.x * 64) & 1023;
        const int chunk = tid & 7;        // 8 chunks x 16 B = one 128-B d-row
        const int dr    = tid >> 3;       // 0..31
#pragma unroll
        for (int rep = 0; rep < 4; ++rep) {
            int d = rep * 32 + dr;
            bf16x8 u = *(const bf16x8*)&T[d * 72 + chunk * 8];
            *(bf16x8*)&vto[((size_t)bt * DC + d) * NC + n0 + chunk * 8] = u;
        }
    } else {
#pragma unroll
        for (int t = 0; t < 8; ++t) {
            int c = t * 16 + l15;
            float b = bias[c];
#pragma unroll
            for (int r = 0; r < 4; ++r) {
                int row = rowA + quad * 4 + r;
                float val = (acc[t][r] + b) * scale;
                ((y == 0) ? qo : ko)[(size_t)row * DC + c] = f2bf(val);
            }
        }
    }
}

// out-projection: bf16 ctx in, fp32 out
__global__ __launch_bounds__(256)
void proj_out(const short* __restrict__ cbf, const short* __restrict__ Wobf,
              const float* __restrict__ bo, float* __restrict__ out)
{
    const int tid  = threadIdx.x;
    const int wave = tid >> 6;
    const int lane = tid & 63;
    const int l15  = lane & 15;
    const int quad = lane >> 4;
    const int rowA = blockIdx.x * 64 + wave * 16;

    f32x4 acc[8];
#pragma unroll
    for (int t = 0; t < 8; ++t) acc[t] = (f32x4){0.f, 0.f, 0.f, 0.f};

#pragma unroll
    for (int kk = 0; kk < DC; kk += 32) {
        bf16x8 Af = *(const bf16x8*)&cbf[(size_t)(rowA + l15) * DC + kk + quad * 8];
#pragma unroll
        for (int t = 0; t < 8; ++t) {
            bf16x8 Bf = *(const bf16x8*)&Wobf[(t * 16 + l15) * DC + kk + quad * 8];
            acc[t] = __builtin_amdgcn_mfma_f32_16x16x32_bf16(Af, Bf, acc[t], 0, 0, 0);
        }
    }

#pragma unroll
    for (int t = 0; t < 8; ++t) {
        int c = t * 16 + l15;
        float b = bo[c];
#pragma unroll
        for (int r = 0; r < 4; ++r) {
            int row = rowA + quad * 4 + r;
            out[(size_t)row * DC + c] = acc[t][r] + b;
        }
    }
}

// ---------------- MFMA attention, barrier-free, prefetched ------------------
// block = 256 thr = 4 waves = 4 heads; grid (32 qt, 16 bt, 2 hz).
// Per wave (1 head, 32 q-rows), per 32-key tile jt:
//   S^T = K·Q^T in ONE v_mfma_f32_32x32x16_bf16 (k = d = 16, no zero-pad):
//       D[key=(reg&3)+8*(reg>>2)+4*hi][q=l31]
//   P = exp2(S^T)·adj : adj read DIRECTLY from global (float4 per reg-group;
//       4 waves/block share the tile via L1; no LDS staging, no __syncthreads)
//   P -> wave-private LDS (4 b64 writes), read back as 2 b128 A-frags
//   ctx += P·V, w += P·ones : 16x16x32 MFMAs per q-subtile s
// Next tile's K/V/adj are prefetched into named registers before compute.
__global__ __launch_bounds__(256, 4)
void attn_kernel(const short* __restrict__ qb, const short* __restrict__ kb,
                 const short* __restrict__ vt, const float* __restrict__ adj,
                 short* __restrict__ cb)
{
    __shared__ short Ps[4][32 * 40];     // wave-private P scratch (10.2 KB)

    const int tid  = threadIdx.x;
    const int wave = tid >> 6;
    const int lane = tid & 63;
    const int l31  = lane & 31;
    const int hi   = lane >> 5;
    const int l15  = lane & 15;
    const int quad = lane >> 4;
    const int bt   = blockIdx.y;
    const int qt0  = blockIdx.x * 32;
    const int h    = blockIdx.z * 4 + wave;

    const size_t xb = (size_t)bt * NC * DC;
    const size_t ab = (size_t)bt * NC * NC;

    // Q B-frag for 32x32x16: B[k=d=hi*8+j][n=q=l31] (QSCALE folded at proj)
    const bf16x8 Bq = *(const bf16x8*)&qb[xb + (size_t)(qt0 + l31) * DC + h * HDC + hi * 8];

    PK8 ones;
#pragma unroll
    for (int j = 0; j < 8; ++j) ones.s[j] = (short)0x3F80;   // bf16 1.0

    f32x4 Cc[2], Cw[2];
#pragma unroll
    for (int s = 0; s < 2; ++s) {
        Cc[s] = (f32x4){0.f, 0.f, 0.f, 0.f};
        Cw[s] = (f32x4){0.f, 0.f, 0.f, 0.f};
    }

    short* Pw = &Ps[wave][0];

    const short* kp = kb + xb + h * HDC + hi * 8;                    // + (jt+l31)*DC
    const short* vp = vt + ((size_t)bt * DC + h * HDC + l15) * NC;   // + jt + quad*8
    const float* ap = adj + ab + (size_t)(qt0 + l31) * NC + hi * 4;  // + jt + t*8

    // prefetch jt = 0
    bf16x8 Ak = *(const bf16x8*)&kp[(size_t)l31 * DC];
    bf16x8 Bv = *(const bf16x8*)&vp[quad * 8];
    float4 a0 = *(const float4*)&ap[0];
    float4 a1 = *(const float4*)&ap[8];
    float4 a2 = *(const float4*)&ap[16];
    float4 a3 = *(const float4*)&ap[24];

    for (int jt = 0; jt < NC; jt += 32) {
        const int nj = (jt + 32) & (NC - 1);   // wrap: last prefetch is dead
        bf16x8 Akn = *(const bf16x8*)&kp[(size_t)(nj + l31) * DC];
        bf16x8 Bvn = *(const bf16x8*)&vp[nj + quad * 8];
        float4 b0  = *(const float4*)&ap[nj + 0];
        float4 b1  = *(const float4*)&ap[nj + 8];
        float4 b2  = *(const float4*)&ap[nj + 16];
        float4 b3  = *(const float4*)&ap[nj + 24];

        f32x16 S;
#pragma unroll
        for (int i = 0; i < 16; ++i) S[i] = 0.f;
        S = __builtin_amdgcn_mfma_f32_32x32x16_bf16(Ak, Bq, S, 0, 0, 0);

        // P[q=l31][key 8t+4hi+r] = exp2(S)*adj, packed bf16 -> wave-private LDS
#define EXPGRP(t, A)                                                          \
        {                                                                     \
            float p0 = EXP2F(S[4*t+0]) * A.x;                                 \
            float p1 = EXP2F(S[4*t+1]) * A.y;                                 \
            float p2 = EXP2F(S[4*t+2]) * A.z;                                 \
            float p3 = EXP2F(S[4*t+3]) * A.w;                                 \
            PK2 pk;                                                           \
            pk.h2[0] = __float22bfloat162_rn(make_float2(p0, p1));            \
            pk.h2[1] = __float22bfloat162_rn(make_float2(p2, p3));            \
            *(short4v*)&Pw[l31 * 40 + t * 8 + hi * 4] = pk.s4;                \
        }
        EXPGRP(0, a0)
        EXPGRP(1, a1)
        EXPGRP(2, a2)
        EXPGRP(3, a3)
#undef EXPGRP
        __builtin_amdgcn_wave_barrier();

        // PV + row-sum: A[m=q=s*16+l15][k=key=quad*8+j]
#pragma unroll
        for (int s = 0; s < 2; ++s) {
            bf16x8 Ap = *(const bf16x8*)&Pw[(s * 16 + l15) * 40 + quad * 8];
            Cc[s] = __builtin_amdgcn_mfma_f32_16x16x32_bf16(Ap, Bv, Cc[s], 0, 0, 0);
            Cw[s] = __builtin_amdgcn_mfma_f32_16x16x32_bf16(Ap, ones.v, Cw[s], 0, 0, 0);
        }

        Ak = Akn; Bv = Bvn; a0 = b0; a1 = b1; a2 = b2; a3 = b3;
    }

    // epilogue: ctx[q][d] = Cc/Cw, rows q = s*16+quad*4+r, col d = l15
#pragma unroll
    for (int s = 0; s < 2; ++s)
#pragma unroll
        for (int r = 0; r < 4; ++r) {
            float den = Cw[s][r];
            float rcp = den > 0.f ? 1.f / den : 0.f;
            int row = qt0 + s * 16 + quad * 4 + r;
            cb[xb + (size_t)row * DC + h * HDC + l15] = f2bf(Cc[s][r] * rcp);
        }
}

extern "C" void kernel_launch(void* const* d_in, const int* in_sizes, int n_in,
                              void* d_out, int out_size, void* d_ws, size_t ws_size,
                              hipStream_t stream)
{
    const float* x   = (const float*)d_in[0];
    const float* adj = (const float*)d_in[1];
    const float* Wq  = (const float*)d_in[2];
    const float* bq  = (const float*)d_in[3];
    const float* Wk  = (const float*)d_in[4];
    const float* bk  = (const float*)d_in[5];
    const float* Wv  = (const float*)d_in[6];
    const float* bv  = (const float*)d_in[7];
    const float* Wo  = (const float*)d_in[8];
    const float* bo  = (const float*)d_in[9];
    float* out = (float*)d_out;

    const size_t tok = (size_t)BTC * NC * DC;   // 2,097,152
    short* xbf  = (short*)d_ws;
    short* Wbf  = xbf  + tok;        // 4 * 16384
    short* qbuf = Wbf  + 65536;
    short* kbuf = qbuf + tok;
    short* vt   = kbuf + tok;
    short* cbuf = vt   + tok;

    prep_kernel<<<2112, 256, 0, stream>>>(x, Wq, Wk, Wv, Wo, xbf, Wbf);

    dim3 pgrid(256, 3);
    proj_qkv<<<pgrid, 256, 0, stream>>>(xbf, Wbf, bq, bk, bv, qbuf, kbuf, vt);

    dim3 agrid(32, 16, 2);
    attn_kernel<<<agrid, 256, 0, stream>>>(qbuf, kbuf, vt, adj, cbuf);

    proj_out<<<256, 256, 0, stream>>>(cbuf, Wbf + 3 * 16384, bo, out);
}

// Round 2
// 167.023 us; speedup vs baseline: 1.3241x; 1.3241x over previous
//
#include <hip/hip_runtime.h>
#include <hip/hip_bf16.h>

#define BTC 16
#define NC 1024
#define DC 128
#define HC 8
#define HDC 16

typedef __attribute__((ext_vector_type(8))) short bf16x8;   // 8 bf16 = 4 VGPR
typedef __attribute__((ext_vector_type(4))) float f32x4;    // MFMA C/D frag 16x16
typedef __attribute__((ext_vector_type(16))) float f32x16;  // MFMA C/D frag 32x32
typedef __attribute__((ext_vector_type(4))) short short4v;  // 8B pack

#if __has_builtin(__builtin_amdgcn_exp2f)
#define EXP2F(x) __builtin_amdgcn_exp2f(x)
#else
#define EXP2F(x) exp2f(x)
#endif

// q scale: 0.25 (1/sqrt(HD)) * log2(e)  -> attention uses exp2 directly
#define QSCALE 0.36067376022224085f

union PK2 { short4v s4; __hip_bfloat162 h2[2]; };
union PK8 { bf16x8 v; short s[8]; __hip_bfloat162 h2[4]; };

static __device__ inline short f2bf(float f) {               // RNE f32->bf16
    unsigned u = __builtin_bit_cast(unsigned, f);
    u += 0x7fffu + ((u >> 16) & 1u);
    return (short)(u >> 16);
}

// raw workgroup barrier: LDS-visibility only (lgkmcnt), keeps global register
// prefetches (vmcnt) in flight across the barrier (unlike __syncthreads).
#define LDS_BARRIER()                                              \
    do {                                                           \
        asm volatile("s_waitcnt lgkmcnt(0)" ::: "memory");         \
        __builtin_amdgcn_s_barrier();                              \
        asm volatile("" ::: "memory");                             \
    } while (0)

// ---------------- prep: fp32 -> bf16 for x and the 4 weight matrices --------
__global__ __launch_bounds__(256)
void prep_kernel(const float* __restrict__ x,
                 const float* __restrict__ Wq, const float* __restrict__ Wk,
                 const float* __restrict__ Wv, const float* __restrict__ Wo,
                 short* __restrict__ xbf, short* __restrict__ Wbf)
{
    int gid  = blockIdx.x * 256 + threadIdx.x;
    int base = gid * 4;
    const float* src;
    short* dst;
    if (base < 2097152) {                      // x: 16*1024*128
        src = x + base; dst = xbf + base;
    } else {
        int idx = base - 2097152;              // 0..65535 over 4 W's
        int w   = idx >> 14;
        int off = idx & 16383;
        src = ((w == 0) ? Wq : (w == 1) ? Wk : (w == 2) ? Wv : Wo) + off;
        dst = Wbf + w * 16384 + off;
    }
    float4 v = *(const float4*)src;
    PK2 pk;
    pk.h2[0] = __float22bfloat162_rn(make_float2(v.x, v.y));
    pk.h2[1] = __float22bfloat162_rn(make_float2(v.z, v.w));
    *(short4v*)dst = pk.s4;
}

// ---------------- MFMA projection, C = X @ W^T + b --------------------------
// block = 256 thr (4 waves), wave = 16 rows x 128 cols, K-loop 4x32.
// y = 0: q (scale QSCALE), 1: k — BOTH stored head-packed [bt][h][n][16] so
// the attention kernel's per-tile K load is one fully-coalesced 1KB wave load.
// y = 2: v stored transposed vt[bt][d][n] via LDS transpose -> 16B stores.
__global__ __launch_bounds__(256)
void proj_qkv(const short* __restrict__ xbf, const short* __restrict__ Wbf,
              const float* __restrict__ bq, const float* __restrict__ bk,
              const float* __restrict__ bv,
              short* __restrict__ qo, short* __restrict__ ko, short* __restrict__ vto)
{
    __shared__ short T[128 * 72];        // 18.4 KB transpose tile (y==2 only)

    const int y = blockIdx.y;
    const short* W = Wbf + y * 16384;
    const float* bias = (y == 0) ? bq : (y == 1) ? bk : bv;
    const float scale = (y == 0) ? QSCALE : 1.0f;

    const int tid  = threadIdx.x;
    const int wave = tid >> 6;
    const int lane = tid & 63;
    const int l15  = lane & 15;
    const int quad = lane >> 4;
    const int rowA = blockIdx.x * 64 + wave * 16;

    f32x4 acc[8];
#pragma unroll
    for (int t = 0; t < 8; ++t) acc[t] = (f32x4){0.f, 0.f, 0.f, 0.f};

#pragma unroll
    for (int kk = 0; kk < DC; kk += 32) {
        bf16x8 Af = *(const bf16x8*)&xbf[(size_t)(rowA + l15) * DC + kk + quad * 8];
#pragma unroll
        for (int t = 0; t < 8; ++t) {
            bf16x8 Bf = *(const bf16x8*)&W[(t * 16 + l15) * DC + kk + quad * 8];
            acc[t] = __builtin_amdgcn_mfma_f32_16x16x32_bf16(Af, Bf, acc[t], 0, 0, 0);
        }
    }

    if (y == 2) {
        // transpose through LDS: T[c][local_row], row stride 72 shorts (144 B,
        // 16-B aligned for b128 reads; bank-minimal b64 writes)
#pragma unroll
        for (int t = 0; t < 8; ++t) {
            int c = t * 16 + l15;
            float b = bias[c];
            PK2 pk;
            pk.h2[0] = __float22bfloat162_rn(make_float2(acc[t][0] + b, acc[t][1] + b));
            pk.h2[1] = __float22bfloat162_rn(make_float2(acc[t][2] + b, acc[t][3] + b));
            *(short4v*)&T[c * 72 + wave * 16 + quad * 4] = pk.s4;
        }
        __syncthreads();                  // y uniform per block: no divergence
        const int bt = blockIdx.x >> 4;
        const int n0 = (blockIdx.x * 64) & 1023;
        const int chunk = tid & 7;        // 8 chunks x 16 B = one 128-B d-row
        const int dr    = tid >> 3;       // 0..31
#pragma unroll
        for (int rep = 0; rep < 4; ++rep) {
            int d = rep * 32 + dr;
            bf16x8 u = *(const bf16x8*)&T[d * 72 + chunk * 8];
            *(bf16x8*)&vto[((size_t)bt * DC + d) * NC + n0 + chunk * 8] = u;
        }
    } else {
        short* dst = (y == 0) ? qo : ko;
#pragma unroll
        for (int t = 0; t < 8; ++t) {
            int c  = t * 16 + l15;
            int hh = c >> 4, dd = c & 15;
            float b = bias[c];
#pragma unroll
            for (int r = 0; r < 4; ++r) {
                int row = rowA + quad * 4 + r;       // = bt*1024 + n
                int btq = row >> 10, n = row & 1023;
                float val = (acc[t][r] + b) * scale;
                dst[(((size_t)btq * HC + hh) * NC + n) * HDC + dd] = f2bf(val);
            }
        }
    }
}

// out-projection: bf16 ctx in, fp32 out
__global__ __launch_bounds__(256)
void proj_out(const short* __restrict__ cbf, const short* __restrict__ Wobf,
              const float* __restrict__ bo, float* __restrict__ out)
{
    const int tid  = threadIdx.x;
    const int wave = tid >> 6;
    const int lane = tid & 63;
    const int l15  = lane & 15;
    const int quad = lane >> 4;
    const int rowA = blockIdx.x * 64 + wave * 16;

    f32x4 acc[8];
#pragma unroll
    for (int t = 0; t < 8; ++t) acc[t] = (f32x4){0.f, 0.f, 0.f, 0.f};

#pragma unroll
    for (int kk = 0; kk < DC; kk += 32) {
        bf16x8 Af = *(const bf16x8*)&cbf[(size_t)(rowA + l15) * DC + kk + quad * 8];
#pragma unroll
        for (int t = 0; t < 8; ++t) {
            bf16x8 Bf = *(const bf16x8*)&Wobf[(t * 16 + l15) * DC + kk + quad * 8];
            acc[t] = __builtin_amdgcn_mfma_f32_16x16x32_bf16(Af, Bf, acc[t], 0, 0, 0);
        }
    }

#pragma unroll
    for (int t = 0; t < 8; ++t) {
        int c = t * 16 + l15;
        float b = bo[c];
#pragma unroll
        for (int r = 0; r < 4; ++r) {
            int row = rowA + quad * 4 + r;
            out[(size_t)row * DC + c] = acc[t][r] + b;
        }
    }
}

// ---------------- MFMA attention: staged adj + prefetch + pipelined P -------
// block = 512 thr = 8 waves = 8 heads; grid (32 qt, 16 bt). Per wave: 32 q x
// all 1024 keys for one head. Per 32-key tile it:
//   S^T = K·Q^T in ONE v_mfma_f32_32x32x16_bf16 (k=d=16):
//       D[key=(reg&3)+8*(reg>>2)+4*hi][q=l31]
//   P = exp2(S^T)·adj (adj from coalesced-staged LDS tile, double-buffered)
//   P -> wave-private LDS buf[it&1]; PV of tile it-1 reads buf[(it-1)&1]
//       (write->read latency hidden under barrier+QK+exp of the next tile)
// K/V frags + adj staging rows prefetched 1 tile ahead in registers; the raw
// LDS_BARRIER (lgkmcnt only) keeps them in flight across the barrier.
__global__ __launch_bounds__(512, 4)
void attn_kernel(const short* __restrict__ qh, const short* __restrict__ kh,
                 const short* __restrict__ vt, const float* __restrict__ adj,
                 short* __restrict__ cb)
{
    __shared__ float As[2][32 * 36];     // adj tile, double-buffered (9.2 KB)
    __shared__ short Ps[8][2][32 * 40];  // wave-private P, double-buffered (41 KB)

    const int tid  = threadIdx.x;
    const int wave = tid >> 6;           // = head h
    const int lane = tid & 63;
    const int l31  = lane & 31;
    const int hi   = lane >> 5;
    const int l15  = lane & 15;
    const int quad = lane >> 4;
    const int bt   = blockIdx.y;
    const int qt0  = blockIdx.x * 32;
    const int h    = wave;

    const size_t xb = (size_t)bt * NC * DC;
    const size_t hb = ((size_t)bt * HC + h) * NC;    // head-packed row base

    const short* kp = kh + hb * HDC + hi * 8;                        // + (key)*16
    const short* vp = vt + ((size_t)bt * DC + h * HDC + l15) * NC;   // + key + quad*8
    const int arow = tid >> 4;                                       // 0..31
    const int acol = (tid & 15) * 2;
    const float* aptr = adj + (size_t)bt * NC * NC + (size_t)(qt0 + arow) * NC + acol;

    // issue order matters: ar first (consumed first), then K/V
    float2 ar  = *(const float2*)aptr;                               // adj tile 0
    bf16x8 Ak  = *(const bf16x8*)&kp[(size_t)l31 * HDC];             // K tile 0
    bf16x8 Bv  = *(const bf16x8*)&vp[quad * 8];                      // V tile 0
    const bf16x8 Bq = *(const bf16x8*)&qh[(hb + qt0 + l31) * HDC + hi * 8];

    PK8 ones;
#pragma unroll
    for (int j = 0; j < 8; ++j) ones.s[j] = (short)0x3F80;   // bf16 1.0

    f32x16 Z16;
#pragma unroll
    for (int i = 0; i < 16; ++i) Z16[i] = 0.f;               // hoisted zero C

    f32x4 Cc[2], Cw[2];
#pragma unroll
    for (int s = 0; s < 2; ++s) {
        Cc[s] = (f32x4){0.f, 0.f, 0.f, 0.f};
        Cw[s] = (f32x4){0.f, 0.f, 0.f, 0.f};
    }

    // P = exp2(S)*adj for one 32-key tile -> bf16 -> wave-private LDS buffer.
    // key = r + 8t + 4hi; adj col block t*8+hi*4; P[q=l31][key].
#define EXPTILE(Sv, abuf, Pc)                                                 \
    do {                                                                      \
        _Pragma("unroll")                                                     \
        for (int t = 0; t < 4; ++t) {                                         \
            float4 a4 = *(const float4*)&As[abuf][l31 * 36 + t * 8 + hi * 4]; \
            float p0 = EXP2F(Sv[4 * t + 0]) * a4.x;                           \
            float p1 = EXP2F(Sv[4 * t + 1]) * a4.y;                           \
            float p2 = EXP2F(Sv[4 * t + 2]) * a4.z;                           \
            float p3 = EXP2F(Sv[4 * t + 3]) * a4.w;                           \
            PK2 pk;                                                           \
            pk.h2[0] = __float22bfloat162_rn(make_float2(p0, p1));            \
            pk.h2[1] = __float22bfloat162_rn(make_float2(p2, p3));            \
            *(short4v*)&Pc[l31 * 40 + t * 8 + hi * 4] = pk.s4;                \
        }                                                                     \
    } while (0)

    // ---- prologue: tile 0 (QK + exp only; PV lags by one tile) ----
    {
        *(float2*)&As[0][arow * 36 + acol] = ar;       // waits ar only (vmcnt(2))
        float2 arn = *(const float2*)(aptr + 32);      // prefetch adj tile 1
        LDS_BARRIER();
        bf16x8 Akn = *(const bf16x8*)&kp[(size_t)(32 + l31) * HDC];
        bf16x8 Bvn = *(const bf16x8*)&vp[32 + quad * 8];
        f32x16 S = __builtin_amdgcn_mfma_f32_32x32x16_bf16(Ak, Bq, Z16, 0, 0, 0);
        short* Pc = &Ps[wave][0][0];
        EXPTILE(S, 0, Pc);
        Ak = Akn; Bv = Bvn; ar = arn;
    }
    bf16x8 Bvp = Bv;   // placeholder; fixed below (V of tile 0 already rotated)

    // NOTE: after prologue rotation Ak/Bv hold tile 1, but PV needs V(0).
    // Redo rotation properly: keep V(0) in Bvp before it was overwritten.
    // (Handled by ordering below: Bvp was set from Bv AFTER rotation — wrong.)
    // -> corrected: we re-load V(0) cheaply from L1 (one b128, L1-hot).
    Bvp = *(const bf16x8*)&vp[quad * 8];

#pragma unroll 2
    for (int it = 1; it < 32; ++it) {
        const int jt  = it * 32;
        const int cur = it & 1, prv = cur ^ 1;

        *(float2*)&As[cur][arow * 36 + acol] = ar;     // waits ar (vmcnt(2))
        float2 arn = *(const float2*)(aptr + ((jt + 32) & (NC - 1)));
        LDS_BARRIER();

        const int nj = (jt + 32) & (NC - 1);           // wrap: last prefetch dead
        bf16x8 Akn = *(const bf16x8*)&kp[(size_t)(nj + l31) * HDC];
        bf16x8 Bvn = *(const bf16x8*)&vp[nj + quad * 8];

        // early P reads of tile it-1 (latency hides under QK+exp)
        const short* Pr = &Ps[wave][prv][0];
        bf16x8 Ap0 = *(const bf16x8*)&Pr[l15 * 40 + quad * 8];
        bf16x8 Ap1 = *(const bf16x8*)&Pr[(16 + l15) * 40 + quad * 8];

        f32x16 S = __builtin_amdgcn_mfma_f32_32x32x16_bf16(Ak, Bq, Z16, 0, 0, 0);
        short* Pc = &Ps[wave][cur][0];
        EXPTILE(S, cur, Pc);

        __builtin_amdgcn_s_setprio(1);
        Cc[0] = __builtin_amdgcn_mfma_f32_16x16x32_bf16(Ap0, Bvp, Cc[0], 0, 0, 0);
        Cw[0] = __builtin_amdgcn_mfma_f32_16x16x32_bf16(Ap0, ones.v, Cw[0], 0, 0, 0);
        Cc[1] = __builtin_amdgcn_mfma_f32_16x16x32_bf16(Ap1, Bvp, Cc[1], 0, 0, 0);
        Cw[1] = __builtin_amdgcn_mfma_f32_16x16x32_bf16(Ap1, ones.v, Cw[1], 0, 0, 0);
        __builtin_amdgcn_s_setprio(0);

        Ak = Akn; Bvp = Bv; Bv = Bvn; ar = arn;
    }

    // ---- epilogue: PV of the last tile (it=31, P in buffer 1, V in Bvp) ----
    {
        const short* Pr = &Ps[wave][1][0];
        bf16x8 Ap0 = *(const bf16x8*)&Pr[l15 * 40 + quad * 8];
        bf16x8 Ap1 = *(const bf16x8*)&Pr[(16 + l15) * 40 + quad * 8];
        Cc[0] = __builtin_amdgcn_mfma_f32_16x16x32_bf16(Ap0, Bvp, Cc[0], 0, 0, 0);
        Cw[0] = __builtin_amdgcn_mfma_f32_16x16x32_bf16(Ap0, ones.v, Cw[0], 0, 0, 0);
        Cc[1] = __builtin_amdgcn_mfma_f32_16x16x32_bf16(Ap1, Bvp, Cc[1], 0, 0, 0);
        Cw[1] = __builtin_amdgcn_mfma_f32_16x16x32_bf16(Ap1, ones.v, Cw[1], 0, 0, 0);
    }

    // epilogue: ctx[q][d] = Cc/Cw, rows q = s*16+quad*4+r, col d = l15
#pragma unroll
    for (int s = 0; s < 2; ++s)
#pragma unroll
        for (int r = 0; r < 4; ++r) {
            float den = Cw[s][r];
            float rcp = den > 0.f ? 1.f / den : 0.f;
            int row = qt0 + s * 16 + quad * 4 + r;
            cb[xb + (size_t)row * DC + h * HDC + l15] = f2bf(Cc[s][r] * rcp);
        }
#undef EXPTILE
}

extern "C" void kernel_launch(void* const* d_in, const int* in_sizes, int n_in,
                              void* d_out, int out_size, void* d_ws, size_t ws_size,
                              hipStream_t stream)
{
    const float* x   = (const float*)d_in[0];
    const float* adj = (const float*)d_in[1];
    const float* Wq  = (const float*)d_in[2];
    const float* bq  = (const float*)d_in[3];
    const float* Wk  = (const float*)d_in[4];
    const float* bk  = (const float*)d_in[5];
    const float* Wv  = (const float*)d_in[6];
    const float* bv  = (const float*)d_in[7];
    const float* Wo  = (const float*)d_in[8];
    const float* bo  = (const float*)d_in[9];
    float* out = (float*)d_out;

    const size_t tok = (size_t)BTC * NC * DC;   // 2,097,152
    short* xbf  = (short*)d_ws;
    short* Wbf  = xbf  + tok;        // 4 * 16384
    short* qbuf = Wbf  + 65536;      // head-packed [bt][h][n][16]
    short* kbuf = qbuf + tok;        // head-packed [bt][h][n][16]
    short* vt   = kbuf + tok;        // transposed  [bt][d][n]
    short* cbuf = vt   + tok;

    prep_kernel<<<2112, 256, 0, stream>>>(x, Wq, Wk, Wv, Wo, xbf, Wbf);

    dim3 pgrid(256, 3);
    proj_qkv<<<pgrid, 256, 0, stream>>>(xbf, Wbf, bq, bk, bv, qbuf, kbuf, vt);

    dim3 agrid(32, 16);
    attn_kernel<<<agrid, 512, 0, stream>>>(qbuf, kbuf, vt, adj, cbuf);

    proj_out<<<256, 256, 0, stream>>>(cbuf, Wbf + 3 * 16384, bo, out);
}